// Round 15
// baseline (1778.589 us; speedup 1.0000x reference)
//
#include <hip/hip_runtime.h>
#include <cstdint>
#include <cstddef>

// LearnableCA fire-spread, round 15: 4-wave (256T) convs with per-wave NCS=1
// (72 weight VGPRs -> no r8-style spill) => 16 waves/CU (was 8). Same proven
// r6 schedule: 8-slot ring, 2-phase-ahead counted-vmcnt staging. Applied to
// encoder convs (k_convM4) and fused step conv (k_convF, 4 waves co x px).

#define HWSZ 65536

typedef _Float16 f16;
typedef f16 f16x8 __attribute__((ext_vector_type(8)));
typedef f16 f16x4 __attribute__((ext_vector_type(4)));
typedef float f32x4 __attribute__((ext_vector_type(4)));

#define GLDS16(gp, lp)                                                        \
  __builtin_amdgcn_global_load_lds(                                           \
      (const __attribute__((address_space(1))) void*)(gp),                    \
      (__attribute__((address_space(3))) void*)(lp), 16, 0, 0)

// ---- conv1 weight prep: [64][22][3][3] -> [co][tap*32+ci], ci7 x64, pad->32 ----
__global__ void k_wprepC0(const float* __restrict__ src, f16* __restrict__ dst) {
  int i = blockIdx.x * 256 + threadIdx.x;
  if (i >= 64 * 288) return;
  int co = i / 288, k = i - co * 288;
  int tap = k >> 5, ci = k & 31;
  float v = 0.f;
  if (ci < 22) {
    v = src[(co * 22 + ci) * 9 + tap];
    if (ci == 7) v *= 64.f;
  }
  dst[i] = (f16)v;
}

// ---- fp16 weight prep: [co][ci 64][3][3] -> [co][tap*64+ci] ----
__global__ void k_wprep64(const float* __restrict__ src, f16* __restrict__ dst,
                          int COUT) {
  int i = blockIdx.x * 256 + threadIdx.x;
  if (i >= COUT * 576) return;
  int co = i / 576, k = i - co * 576;
  int tap = k >> 6, ci = k & 63;
  dst[i] = (f16)src[(co * 64 + ci) * 9 + tap];
}

// ---- cw1 env-part prep (stride-68 source): -> [co][tap*64+ci] ----
__global__ void k_wprepC1env(const float* __restrict__ src, f16* __restrict__ dst) {
  int i = blockIdx.x * 256 + threadIdx.x;
  if (i >= 64 * 576) return;
  int co = i / 576, k = i - co * 576;
  int tap = k >> 6, ci = k & 63;
  dst[i] = (f16)src[(co * 68 + ci) * 9 + tap];
}

// ---- cw1 one-hot table: [9][5][72] (tap, cls, co); cls=4 -> 0 ----
__global__ void k_wprepOh(const float* __restrict__ src, f16* __restrict__ dst) {
  int i = blockIdx.x * 256 + threadIdx.x;
  if (i >= 9 * 5 * 72) return;
  int tap = i / (5 * 72), r = i - tap * (5 * 72);
  int cls = r / 72, co = r - cls * 72;
  float v = 0.f;
  if (co < 64 && cls < 4) v = src[(co * 68 + 64 + cls) * 9 + tap];
  dst[i] = (f16)v;
}

// ---- cw1 full prep (fallback): 64 ci + one-hot block -> [co][640] ----
__global__ void k_wprepC1(const float* __restrict__ src, f16* __restrict__ dst) {
  int i = blockIdx.x * 256 + threadIdx.x;
  if (i >= 64 * 640) return;
  int co = i / 640, k = i - co * 640;
  float v;
  if (k < 576) {
    int tap = k >> 6, ci = k & 63;
    v = src[(co * 68 + ci) * 9 + tap];
  } else {
    int kl = k - 576;
    int oc = kl & 3, tp = kl >> 2;
    v = (tp < 9) ? src[(co * 68 + 64 + oc) * 9 + tp] : 0.f;
  }
  dst[i] = (f16)v;
}

// ---- fold BN + conv bias into per-channel scale/shift ----
__global__ void k_bnfuse(const float* __restrict__ g, const float* __restrict__ be,
                         const float* __restrict__ m, const float* __restrict__ v,
                         const float* __restrict__ bc, float* __restrict__ s,
                         float* __restrict__ t, int C) {
  int c = threadIdx.x;
  if (c < C) {
    float sc = g[c] * rsqrtf(v[c] + 1e-5f);
    s[c] = sc;
    t[c] = (bc[c] - m[c]) * sc + be[c];
  }
}

// ---- identity scale/shift for the base conv ----
__global__ void k_ident(float* __restrict__ s, float* __restrict__ t) {
  int c = threadIdx.x;
  if (c < 64) { s[c] = 1.f; t[c] = 0.f; }
}

// ---- wind reduction stage 1 ----
__global__ __launch_bounds__(256) void k_windpart(const float* __restrict__ env,
                                                  double* __restrict__ part) {
  int blk = blockIdx.x;
  int b = blk >> 5, j = blk & 31;
  const float4* a7 = (const float4*)(env + (((size_t)(b * 22 + 7)) << 16) + j * 2048);
  const float4* a8 = (const float4*)(env + (((size_t)(b * 22 + 8)) << 16) + j * 2048);
  int tid = threadIdx.x;
  double s7 = 0.0, s8 = 0.0;
  for (int i = tid; i < 512; i += 256) {
    float4 v = a7[i];
    s7 += (double)v.x + (double)v.y + (double)v.z + (double)v.w;
    float4 u = a8[i];
    s8 += (double)u.x + (double)u.y + (double)u.z + (double)u.w;
  }
  __shared__ double r7[256], r8[256];
  r7[tid] = s7; r8[tid] = s8;
  __syncthreads();
  for (int off = 128; off > 0; off >>= 1) {
    if (tid < off) { r7[tid] += r7[tid + off]; r8[tid] += r8[tid + off]; }
    __syncthreads();
  }
  if (tid == 0) {
    part[(b * 32 + j) * 2 + 0] = r7[0];
    part[(b * 32 + j) * 2 + 1] = r8[0];
  }
}

// ---- wind reduction stage 2 ----
__global__ void k_windfin(const double* __restrict__ part,
                          const float* __restrict__ wind_k, float* __restrict__ wke) {
  int b = blockIdx.x;
  if (threadIdx.x != 0) return;
  double s7 = 0.0, s8 = 0.0;
  for (int j = 0; j < 32; ++j) {
    s7 += part[(b * 32 + j) * 2 + 0];
    s8 += part[(b * 32 + j) * 2 + 1];
  }
  float wa = (float)(s7 * (1.0 / 65536.0));
  float wsp = (float)(s8 * (1.0 / 65536.0));
  float wsc = fminf(fmaxf(wsp * (1.f / 20.f), 0.f), 1.f);
  float wk[9];
#pragma unroll
  for (int tp = 0; tp < 9; ++tp) wk[tp] = 0.f;
  for (int d = 0; d < 8; ++d) {
    float diff = fabsf(wa - 45.f * (float)d);
    diff = fminf(diff, 360.f - diff);
    float dw = fmaxf(0.f, 1.f - diff * (1.f / 90.f));
    float eff = (dw > 0.1f && wsc > 0.1f) ? dw * wsc : 0.f;
    for (int tp = 0; tp < 9; ++tp) wk[tp] += eff * wind_k[d * 9 + tp];
  }
  for (int tp = 0; tp < 9; ++tp) wke[b * 9 + tp] = wk[tp];
}

__global__ void k_copy(const float* __restrict__ src, float* __restrict__ dst) {
  int i = blockIdx.x * 256 + threadIdx.x;
  ((float4*)dst)[i] = ((const float4*)src)[i];
}

// ---- zero the 1-px border of a padded NHWC buffer [n][258][258][C] ----
__global__ void k_border(f16* __restrict__ buf, int nimg, int C) {
  int i = blockIdx.x * 256 + threadIdx.x;
  int per = 1028 * C;
  if (i >= nimg * per) return;
  int img = i / per, r = i - img * per;
  int px = r / C, c = r - px * C;
  int h, w;
  if (px < 258) { h = 0; w = px; }
  else if (px < 516) { h = 257; w = px - 258; }
  else if (px < 772) { h = px - 515; w = 0; }
  else { h = px - 771; w = 257; }
  buf[((size_t)(img * 258 + h) * 258 + w) * C + c] = (f16)0.f;
}

// ---- env NCHW fp32 -> padded NHWC fp16 [258][258][32], ch7 * 1/64 ----
__global__ __launch_bounds__(256) void k_env2h(const float* __restrict__ env,
                                               f16* __restrict__ dst, int nimg) {
  int i = blockIdx.x * 256 + threadIdx.x;
  if (i >= (nimg << 16)) return;
  int b = i >> 16, hw = i & 65535;
  int h = hw >> 8, w = hw & 255;
  const float* sp = env + (((size_t)b * 22) << 16) + hw;
  f16 o[32];
#pragma unroll
  for (int c = 0; c < 22; ++c) {
    float v = sp[(size_t)c << 16];
    if (c == 7) v *= (1.f / 64.f);
    o[c] = (f16)v;
  }
#pragma unroll
  for (int c = 22; c < 32; ++c) o[c] = (f16)0.f;
  f16* dp = dst + ((size_t)(b * 258 + h + 1) * 258 + (w + 1)) * 32;
  *(f16x8*)(dp + 0) = *(f16x8*)&o[0];
  *(f16x8*)(dp + 8) = *(f16x8*)&o[8];
  *(f16x8*)(dp + 16) = *(f16x8*)&o[16];
  *(f16x8*)(dp + 24) = *(f16x8*)&o[24];
}

// ---- padded uint8 fire-class map: [b][258][258], border=4 ----
__global__ void k_firemap(const float* __restrict__ fire, unsigned char* __restrict__ map,
                          int nimg) {
  int i = blockIdx.x * 256 + threadIdx.x;
  if (i >= nimg * 66564) return;
  int b = i / 66564, r = i - b * 66564;
  int h = r / 258, w = r - h * 258;
  unsigned char v = 4;
  if (h >= 1 && h <= 256 && w >= 1 && w <= 256) {
    float f = fire[((size_t)b << 16) + ((h - 1) << 8) + (w - 1)];
    v = f < 0.25f ? 0 : (f < 0.75f ? 1 : 2);
  }
  map[i] = v;
}

// ---- 4-wave MFMA conv: COUT=64, per-wave 16 couts x 32 px; 8-slot ring ----
template <int CIN, int NS, bool OUTPAD, bool RELU>
__global__ __launch_bounds__(256, 4) void k_convM4(
    const f16* __restrict__ x, const f16* __restrict__ Wp,
    const float* __restrict__ scale, const float* __restrict__ shift,
    f16* __restrict__ y, int NB) {
  constexpr int KT = NS * 32;
  constexpr int CC = CIN / 8;
  constexpr int PERROW = 34 * CC;   // 272 (64ch) / 136 (32ch)
  constexpr int ROWE = 34 * CIN;
  constexpr int NH = CIN / 32;
  constexpr int NST = 4;                      // stores/wave/phase
  constexpr int SGA = (CIN == 64) ? 4 : 2;    // lead-wave stage instrs/phase
  constexpr int SGB = (CIN == 64) ? 2 : 0;

  __shared__ __align__(16) f16 xs[8][ROWE];
  __shared__ float sst[2][64];

  int tid = threadIdx.x;
  int lane = tid & 63;
  int l15 = lane & 15;
  int g = (lane >> 4) & 3;
  int wid = tid >> 6;
  bool lead = (CIN == 64) ? (wid == 0) : (wid < 3);
  int co_base = wid * 16;

  int d = blockIdx.x;
  int hsn = NB * 8;
  int ws = d / hsn;
  int t = d - ws * hsn;
  int b = t >> 3;
  int hs = t & 7;
  int w0 = ws * 32, h0 = hs * 32;

  f16x8 Af[NS];
  {
    const f16* wb = Wp + (size_t)(co_base + l15) * KT + g * 8;
#pragma unroll
    for (int s = 0; s < NS; ++s) Af[s] = *(const f16x8*)(wb + s * 32);
  }
  if (tid < 64) sst[0][tid] = scale[tid];
  else if (tid < 128) sst[1][tid - 64] = shift[tid - 64];

  auto stage_row = [&](int row) {
    int rs = row > 256 ? 256 : row;
    const f16* src = x + ((size_t)(b * 258 + rs + 1) * 258 + w0) * CIN;
    f16* dst = xs[(row + 1) & 7];
    for (int c = tid; c < PERROW; c += 256) {
      int px = c / CC, cc = c - px * CC;
      int sz = (CIN == 64) ? (px & 7) : ((px >> 1) & 3);
      GLDS16(src + px * CIN + ((cc ^ sz) << 3), dst + c * 8);
    }
  };

#define PHASE_SYNC(NA, NBW)                                               \
  do {                                                                    \
    if (lead)                                                             \
      asm volatile("s_waitcnt vmcnt(%0)" ::"i"(NA) : "memory");           \
    else                                                                  \
      asm volatile("s_waitcnt vmcnt(%0)" ::"i"(NBW) : "memory");          \
    __builtin_amdgcn_s_barrier();                                         \
    __builtin_amdgcn_sched_barrier(0);                                    \
  } while (0)

  // prologue: rows h0-1..h0+4; rows -1..+2 drained, +3/+4 in flight
  stage_row(h0 - 1); stage_row(h0);
  stage_row(h0 + 1); stage_row(h0 + 2);
  stage_row(h0 + 3); stage_row(h0 + 4);
  PHASE_SYNC(SGA, SGB);

#pragma unroll 1
  for (int hp = h0; hp < h0 + 32; hp += 2) {
    stage_row(hp + 5);
    stage_row(hp + 6);
    __builtin_amdgcn_sched_barrier(0);  // stages precede compute+stores

#pragma unroll
    for (int rr = 0; rr < 2; ++rr) {
      int h = hp + rr;
      f32x4 acc[2];
      acc[0] = (f32x4){0.f, 0.f, 0.f, 0.f};
      acc[1] = (f32x4){0.f, 0.f, 0.f, 0.f};
      const f16* sp0 = xs[h & 7];
      const f16* sp1 = xs[(h + 1) & 7];
      const f16* sp2 = xs[(h + 2) & 7];
#pragma unroll
      for (int tap = 0; tap < 9; ++tap) {
        const int dy = tap / 3, dx = tap - 3 * (tap / 3);
        const f16* sp = (dy == 0) ? sp0 : ((dy == 1) ? sp1 : sp2);
#pragma unroll
        for (int pxb = 0; pxb < 2; ++pxb) {
          int pxd = pxb * 16 + l15 + dx;
          int sz = (CIN == 64) ? (pxd & 7) : ((pxd >> 1) & 3);
#pragma unroll
          for (int half = 0; half < NH; ++half) {
            f16x8 bb = *(const f16x8*)(sp + pxd * CIN + (((g + 4 * half) ^ sz) << 3));
            acc[pxb] = __builtin_amdgcn_mfma_f32_16x16x32_f16(
                Af[tap * NH + half], bb, acc[pxb], 0, 0, 0);
          }
        }
      }
      int cb = co_base + 4 * g;
      f32x4 sv = *(const f32x4*)&sst[0][cb];
      f32x4 tv = *(const f32x4*)&sst[1][cb];
#pragma unroll
      for (int pxb = 0; pxb < 2; ++pxb) {
        int px = pxb * 16 + l15;
        f16x4 o;
#pragma unroll
        for (int r = 0; r < 4; ++r) {
          float v = acc[pxb][r] * sv[r] + tv[r];
          o[r] = (f16)(RELU ? fmaxf(v, 0.f) : v);
        }
        size_t oi =
            OUTPAD ? ((size_t)(b * 258 + h + 1) * 258 + (w0 + px + 1)) * 64 + cb
                   : ((size_t)(b * 256 + h) * 256 + (w0 + px)) * 64 + cb;
        *(f16x4*)&y[oi] = o;
      }
    }
    PHASE_SYNC(SGA + NST, SGB + NST);
  }
#undef PHASE_SYNC
}

// ---- fallback MFMA conv (r6 schedule, 2 waves/128T) ----
template <int CIN, int NCS, int NS, bool ONEHOT, bool OUTPAD, bool PXSPLIT, bool RELU>
__global__ __launch_bounds__(128, 2) void k_convM(
    const f16* __restrict__ x, const f16* __restrict__ Wp,
    const float* __restrict__ scale, const float* __restrict__ shift,
    const unsigned char* __restrict__ fmap, f16* __restrict__ y, int NB) {
  constexpr int COUT = PXSPLIT ? NCS * 16 : NCS * 32;
  constexpr int KT = NS * 32;
  constexpr int CC = CIN / 8;
  constexpr int PERROW = 34 * CC;
  constexpr int ROWE = 34 * CIN;
  constexpr int PXW = PXSPLIT ? 1 : 2;
  constexpr int NH = CIN / 32;
  constexpr int VN0 = (CIN == 64) ? 6 : 4;
  constexpr int VN1 = (CIN == 64) ? 4 : 2;

  __shared__ __align__(16) f16 xs[8][ROWE];
  __shared__ float sst[2][COUT];

  int tid = threadIdx.x;
  int lane = tid & 63;
  int l15 = lane & 15;
  int g = (lane >> 4) & 3;
  int wco = tid >> 6;

  int d = blockIdx.x;
  int hsn = NB * 8;
  int ws = d / hsn;
  int t = d - ws * hsn;
  int b = t >> 3;
  int hs = t & 7;
  int w0 = ws * 32, h0 = hs * 32;

  int co_base = PXSPLIT ? 0 : wco * NCS * 16;
  int pxg = PXSPLIT ? wco * 16 : 0;

  f16x8 Af[NCS][NS];
  {
    const f16* wb = Wp + (size_t)(co_base + l15) * KT + g * 8;
#pragma unroll
    for (int cs = 0; cs < NCS; ++cs)
#pragma unroll
      for (int s = 0; s < NS; ++s)
        Af[cs][s] = *(const f16x8*)(wb + cs * 16 * KT + s * 32);
  }
  if (tid < COUT) {
    sst[0][tid] = scale[tid];
    sst[1][tid] = shift[tid];
  }

  auto stage_row = [&](int row) {
    int rs = row > 256 ? 256 : row;
    const f16* src = x + ((size_t)(b * 258 + rs + 1) * 258 + w0) * CIN;
    f16* dst = xs[(row + 1) & 7];
    for (int c = tid; c < PERROW; c += 128) {
      int px = c / CC, cc = c - px * CC;
      int sz = (CIN == 64) ? (px & 7) : ((px >> 1) & 3);
      GLDS16(src + px * CIN + ((cc ^ sz) << 3), dst + c * 8);
    }
  };

#define PHASE_SYNC()                                                      \
  do {                                                                    \
    if (wco == 0)                                                         \
      asm volatile("s_waitcnt vmcnt(%0)" ::"i"(VN0) : "memory");          \
    else                                                                  \
      asm volatile("s_waitcnt vmcnt(%0)" ::"i"(VN1) : "memory");          \
    __builtin_amdgcn_s_barrier();                                         \
    __builtin_amdgcn_sched_barrier(0);                                    \
  } while (0)

  stage_row(h0 - 1); stage_row(h0);
  stage_row(h0 + 1); stage_row(h0 + 2);
  stage_row(h0 + 3); stage_row(h0 + 4);
  PHASE_SYNC();

#pragma unroll 1
  for (int hp = h0; hp < h0 + 32; hp += 2) {
#pragma unroll
    for (int r2 = 0; r2 < 2; ++r2) {
      stage_row(hp + 5 + r2);
      int h = hp + r2;

      f32x4 acc[NCS][PXW];
#pragma unroll
      for (int cs = 0; cs < NCS; ++cs)
#pragma unroll
        for (int p = 0; p < PXW; ++p) acc[cs][p] = (f32x4){0.f, 0.f, 0.f, 0.f};

      int ia[PXW], ib[PXW], ic[PXW];
      if (ONEHOT) {
        int ta = 2 * g, tb = ta + 1;
        int dya = ta / 3, dxa = ta - 3 * dya;
        int dyb = tb / 3, dxb = tb - 3 * dyb;
#pragma unroll
        for (int pxb = 0; pxb < PXW; ++pxb) {
          int pxa = pxg + pxb * 16 + l15;
          ia[pxb] = fmap[(size_t)(b * 258 + h + dya) * 258 + w0 + pxa + dxa];
          ib[pxb] = fmap[(size_t)(b * 258 + h + dyb) * 258 + w0 + pxa + dxb];
          ic[pxb] = fmap[(size_t)(b * 258 + h + 2) * 258 + w0 + pxa + 2];
        }
      }

      const f16* sp0 = xs[h & 7];
      const f16* sp1 = xs[(h + 1) & 7];
      const f16* sp2 = xs[(h + 2) & 7];
#pragma unroll
      for (int tap = 0; tap < 9; ++tap) {
        const int dy = tap / 3, dx = tap - 3 * (tap / 3);
        const f16* sp = (dy == 0) ? sp0 : ((dy == 1) ? sp1 : sp2);
#pragma unroll
        for (int pxb = 0; pxb < PXW; ++pxb) {
          int pxd = pxg + pxb * 16 + l15 + dx;
          int sz = (CIN == 64) ? (pxd & 7) : ((pxd >> 1) & 3);
#pragma unroll
          for (int half = 0; half < NH; ++half) {
            f16x8 bb = *(const f16x8*)(sp + pxd * CIN + (((g + 4 * half) ^ sz) << 3));
#pragma unroll
            for (int cs = 0; cs < NCS; ++cs)
              acc[cs][pxb] = __builtin_amdgcn_mfma_f32_16x16x32_f16(
                  Af[cs][tap * NH + half], bb, acc[cs][pxb], 0, 0, 0);
          }
        }
      }
      if (ONEHOT) {
#pragma unroll
        for (int pxb = 0; pxb < PXW; ++pxb) {
          f16x8 b18, b19;
#pragma unroll
          for (int j = 0; j < 4; ++j) {
            b18[j] = (f16)((ia[pxb] == j) ? 1.f : 0.f);
            b18[j + 4] = (f16)((ib[pxb] == j) ? 1.f : 0.f);
            b19[j] = (f16)((g == 0 && ic[pxb] == j) ? 1.f : 0.f);
            b19[j + 4] = (f16)0.f;
          }
#pragma unroll
          for (int cs = 0; cs < NCS; ++cs) {
            acc[cs][pxb] = __builtin_amdgcn_mfma_f32_16x16x32_f16(
                Af[cs][NS - 2], b18, acc[cs][pxb], 0, 0, 0);
            acc[cs][pxb] = __builtin_amdgcn_mfma_f32_16x16x32_f16(
                Af[cs][NS - 1], b19, acc[cs][pxb], 0, 0, 0);
          }
        }
      }
#pragma unroll
      for (int cs = 0; cs < NCS; ++cs) {
        int cb = co_base + cs * 16 + 4 * g;
        f32x4 sv = *(const f32x4*)&sst[0][cb];
        f32x4 tv = *(const f32x4*)&sst[1][cb];
#pragma unroll
        for (int pxb = 0; pxb < PXW; ++pxb) {
          int px = pxg + pxb * 16 + l15;
          f16x4 o;
#pragma unroll
          for (int r = 0; r < 4; ++r) {
            float v = acc[cs][pxb][r] * sv[r] + tv[r];
            o[r] = (f16)(RELU ? fmaxf(v, 0.f) : v);
          }
          size_t oi =
              OUTPAD ? ((size_t)(b * 258 + h + 1) * 258 + (w0 + px + 1)) * 64 + cb
                     : ((size_t)(b * 256 + h) * 256 + (w0 + px)) * COUT + cb;
          *(f16x4*)&y[oi] = o;
        }
      }
    }
    PHASE_SYNC();
  }
#undef PHASE_SYNC
}

// ---- fused step conv, 4 waves: h1 staged in-kernel from base+onehot ----
// wave = (pxHalf = wid>>1, coHalf = wid&1): 16 couts x 16 px each.
__global__ __launch_bounds__(256, 4) void k_convF(
    const f16* __restrict__ base, const f16* __restrict__ Wp,
    const f16* __restrict__ Woh,
    const float* __restrict__ s1v, const float* __restrict__ t1v,
    const float* __restrict__ s2v, const float* __restrict__ t2v,
    const unsigned char* __restrict__ fmap, f16* __restrict__ y, int NB) {
  constexpr int NS = 18, KT = NS * 32;
  __shared__ __align__(16) f16 xs[6][34 * 64];
  __shared__ f16 tbl[9 * 5 * 72];
  __shared__ float sA[2][64];
  __shared__ float sB[2][32];

  int tid = threadIdx.x;
  int lane = tid & 63;
  int l15 = lane & 15;
  int g = (lane >> 4) & 3;
  int wid = tid >> 6;
  int co_base = (wid & 1) * 16;
  int pxg = (wid >> 1) * 16;

  int d = blockIdx.x;
  int hsn = NB * 8;
  int ws = d / hsn;
  int t = d - ws * hsn;
  int b = t >> 3;
  int hs = t & 7;
  int w0 = ws * 32, h0 = hs * 32;

  f16x8 Af[NS];
  {
    const f16* wb = Wp + (size_t)(co_base + l15) * KT + g * 8;
#pragma unroll
    for (int s = 0; s < NS; ++s) Af[s] = *(const f16x8*)(wb + s * 32);
  }
  for (int i = tid; i < 9 * 5 * 72; i += 256) tbl[i] = Woh[i];
  if (tid < 64) sA[0][tid] = s1v[tid];
  else if (tid < 128) sA[1][tid - 64] = t1v[tid - 64];
  else if (tid < 160) sB[0][tid - 128] = s2v[tid - 128];
  else if (tid < 192) sB[1][tid - 160] = t2v[tid - 160];
  __syncthreads();

  const unsigned char* fmb = fmap + (size_t)b * 66564;

  auto ldchunk = [&](int c, int rb) -> f16x8 {
    int r2 = c >= 272 ? 1 : 0;
    int cc = c - r2 * 272;
    int px = cc >> 3, q = cc & 7;
    int row = rb + r2, col = w0 - 1 + px;
    if ((unsigned)row < 256u && (unsigned)col < 256u)
      return *(const f16x8*)&base[(((size_t)(b * 256 + row)) * 256 + col) * 64 + q * 8];
    f16x8 z = {};
    return z;
  };
  auto xform = [&](int c, int rb, f16x8 a) {
    int r2 = c >= 272 ? 1 : 0;
    int cc = c - r2 * 272;
    int px = cc >> 3, q = cc & 7;
    int row = rb + r2, col = w0 - 1 + px;
    f16* dst = &xs[(row + 1) % 6][px * 64 + ((q ^ (px & 7)) << 3)];
    if ((unsigned)row < 256u && (unsigned)col < 256u) {
      int cls[9];
#pragma unroll
      for (int tap = 0; tap < 9; ++tap)
        cls[tap] = fmb[(size_t)(row + tap / 3) * 258 + col + tap % 3];
#pragma unroll
      for (int tap = 0; tap < 9; ++tap)
        a = a + *(const f16x8*)&tbl[(tap * 5 + cls[tap]) * 72 + q * 8];
      f16x8 o;
#pragma unroll
      for (int j = 0; j < 8; ++j) {
        float v = (float)a[j] * sA[0][q * 8 + j] + sA[1][q * 8 + j];
        o[j] = (f16)fmaxf(v, 0.f);
      }
      *(f16x8*)dst = o;
    } else {
      f16x8 z = {};
      *(f16x8*)dst = z;
    }
  };

  // prologue: rows h0-1..h0+2 (load+transform combined)
  for (int rb = h0 - 1; rb <= h0 + 1; rb += 2)
    for (int c = tid; c < 544; c += 256) xform(c, rb, ldchunk(c, rb));
  __syncthreads();

#pragma unroll 1
  for (int hp = h0; hp < h0 + 32; hp += 2) {
    // issue base loads for rows hp+3, hp+4 (latency hides under MFMA)
    f16x8 la = ldchunk(tid, hp + 3);
    f16x8 lb = ldchunk(tid + 256, hp + 3);
    f16x8 lc = {};
    if (tid < 32) lc = ldchunk(tid + 512, hp + 3);
    __builtin_amdgcn_sched_barrier(0);

    // MFMA rows hp, hp+1 -> h2
#pragma unroll
    for (int rr = 0; rr < 2; ++rr) {
      int h = hp + rr;
      f32x4 acc = (f32x4){0.f, 0.f, 0.f, 0.f};
      const f16* sp0 = xs[h % 6];
      const f16* sp1 = xs[(h + 1) % 6];
      const f16* sp2 = xs[(h + 2) % 6];
#pragma unroll
      for (int tap = 0; tap < 9; ++tap) {
        const int dy = tap / 3, dx = tap - 3 * (tap / 3);
        const f16* sp = (dy == 0) ? sp0 : ((dy == 1) ? sp1 : sp2);
        int pxd = pxg + l15 + dx;
        int sz = pxd & 7;
#pragma unroll
        for (int half = 0; half < 2; ++half) {
          f16x8 bb = *(const f16x8*)(sp + pxd * 64 + (((g + 4 * half) ^ sz) << 3));
          acc = __builtin_amdgcn_mfma_f32_16x16x32_f16(Af[tap * 2 + half], bb, acc,
                                                       0, 0, 0);
        }
      }
      int cb = co_base + 4 * g;
      f32x4 sv = *(const f32x4*)&sB[0][cb];
      f32x4 tv = *(const f32x4*)&sB[1][cb];
      f16x4 o;
#pragma unroll
      for (int r = 0; r < 4; ++r)
        o[r] = (f16)fmaxf(acc[r] * sv[r] + tv[r], 0.f);
      *(f16x4*)&y[((size_t)(b * 256 + h) * 256 + (w0 + pxg + l15)) * 32 + cb] = o;
    }
    __builtin_amdgcn_sched_barrier(0);

    // transform + ds_write staged rows
    xform(tid, hp + 3, la);
    xform(tid + 256, hp + 3, lb);
    if (tid < 32) xform(tid + 512, hp + 3, lc);
    __syncthreads();
  }
}

// ---- fused 1x1 conv (32->4) + softmax + wind conv + fire update + next map ----
__global__ __launch_bounds__(256) void k_step(
    const f16* __restrict__ h2, const float* __restrict__ cw3,
    const float* __restrict__ cb3, const float* __restrict__ wke,
    const float* __restrict__ fin, float* __restrict__ fout,
    float* __restrict__ fout2, unsigned char* __restrict__ mapout) {
  __shared__ float wl[4][32];
  __shared__ float bl[4];
  __shared__ float wk[9];
  int tid = threadIdx.x;
  if (tid < 128) wl[tid >> 5][tid & 31] = cw3[tid];
  if (tid < 4) bl[tid] = cb3[tid];
  int bx = blockIdx.x;
  int b = bx >> 8, h = bx & 255;
  if (tid < 9) wk[tid] = wke[b * 9 + tid];
  __syncthreads();
  int w = tid;
  const f16x8* hp8 = (const f16x8*)(h2 + ((size_t)(b * 256 + h) * 256 + w) * 32);
  float l0 = bl[0], l1 = bl[1], l2 = bl[2], l3 = bl[3];
#pragma unroll
  for (int q = 0; q < 4; ++q) {
    f16x8 v8 = hp8[q];
#pragma unroll
    for (int j = 0; j < 8; ++j) {
      float v = (float)v8[j];
      int c = q * 8 + j;
      l0 += v * wl[0][c];
      l1 += v * wl[1][c];
      l2 += v * wl[2][c];
      l3 += v * wl[3][c];
    }
  }
  float mx = fmaxf(fmaxf(l0, l1), fmaxf(l2, l3));
  float e0 = expf(l0 - mx), e1 = expf(l1 - mx), e2 = expf(l2 - mx), e3 = expf(l3 - mx);
  float inv = 1.f / (e0 + e1 + e2 + e3);
  float p1 = e1 * inv, p2 = e2 * inv;
  const float* fp = fin + ((size_t)b << 16);
  float wacc = 0.f;
#pragma unroll
  for (int tap = 0; tap < 9; ++tap) {
    int dy = tap / 3 - 1, dx = tap % 3 - 1;
    int hh = h + dy, ww2 = w + dx;
    float f = ((unsigned)hh < 256u && (unsigned)ww2 < 256u) ? fp[(hh << 8) + ww2] : 0.f;
    wacc += wk[tap] * f;
  }
  float boost = 0.3f / (1.f + expf(-wacc));
  float fcur = fp[(h << 8) + w];
  float target = 0.5f * p1 + 0.5f * boost + p2;
  float fn = 0.7f * fcur + 0.3f * target;
  fn = fminf(fmaxf(fn, 0.f), 1.f);
  size_t o = ((size_t)b << 16) + (h << 8) + w;
  fout[o] = fn;
  if (fout2) fout2[o] = fn;
  mapout[(size_t)(b * 258 + h + 1) * 258 + (w + 1)] =
      fn < 0.25f ? (unsigned char)0 : (fn < 0.75f ? (unsigned char)1 : (unsigned char)2);
}

extern "C" void kernel_launch(void* const* d_in, const int* in_sizes, int n_in,
                              void* d_out, int out_size, void* d_ws, size_t ws_size,
                              hipStream_t stream) {
  const float* env = (const float*)d_in[0];
  const float* fire0 = (const float*)d_in[1];
  const float* w1 = (const float*)d_in[2];
  const float* b1 = (const float*)d_in[3];
  const float* g1 = (const float*)d_in[4];
  const float* be1 = (const float*)d_in[5];
  const float* m1 = (const float*)d_in[6];
  const float* v1 = (const float*)d_in[7];
  const float* w2 = (const float*)d_in[8];
  const float* b2 = (const float*)d_in[9];
  const float* g2 = (const float*)d_in[10];
  const float* be2 = (const float*)d_in[11];
  const float* m2 = (const float*)d_in[12];
  const float* v2 = (const float*)d_in[13];
  const float* cw1 = (const float*)d_in[14];
  const float* cb1 = (const float*)d_in[15];
  const float* cg1 = (const float*)d_in[16];
  const float* cbe1 = (const float*)d_in[17];
  const float* cm1 = (const float*)d_in[18];
  const float* cv1 = (const float*)d_in[19];
  const float* cw2 = (const float*)d_in[20];
  const float* cb2 = (const float*)d_in[21];
  const float* cg2 = (const float*)d_in[22];
  const float* cbe2 = (const float*)d_in[23];
  const float* cm2 = (const float*)d_in[24];
  const float* cv2 = (const float*)d_in[25];
  const float* cw3 = (const float*)d_in[26];
  const float* cb3 = (const float*)d_in[27];
  const float* windk = (const float*)d_in[28];
  // d_in[29] = num_steps (fixed 5)

  float* out = (float*)d_out;
  float* evo = out + 1048576;

  uint8_t* p = (uint8_t*)d_ws;
  f16* W1p = (f16*)p;           p += 64 * 288 * 2;
  f16* W2p = (f16*)p;           p += 64 * 576 * 2;
  f16* Wc1p = (f16*)p;          p += 64 * 640 * 2;
  f16* Wenv = (f16*)p;          p += 64 * 576 * 2;
  f16* Woh = (f16*)p;           p += 9 * 5 * 72 * 2;
  f16* Wc2p = (f16*)p;          p += 32 * 576 * 2;
  float* s1 = (float*)p;        p += 64 * 4;
  float* t1 = (float*)p;        p += 64 * 4;
  float* s2 = (float*)p;        p += 64 * 4;
  float* t2 = (float*)p;        p += 64 * 4;
  float* sc1 = (float*)p;       p += 64 * 4;
  float* tc1 = (float*)p;       p += 64 * 4;
  float* sc2 = (float*)p;       p += 64 * 4;
  float* tc2 = (float*)p;       p += 64 * 4;
  float* idsc = (float*)p;      p += 64 * 4;
  float* idsh = (float*)p;      p += 64 * 4;
  float* wke = (float*)p;       p += 1024;
  double* wpart = (double*)p;   p += 16 * 32 * 2 * 8;
  unsigned char* fmap = p;      p += 16 * 66564 + 1024;

  const size_t IMGP = (size_t)258 * 258 * 64;
  const size_t IMGP32 = (size_t)258 * 258 * 32;
  const size_t IMGU = (size_t)65536 * 64;
  const size_t S = 16 * IMGP * 2;
  const size_t CH64 = IMGP * 2;
  const size_t CH32 = IMGP32 * 2;
  size_t fixed = (size_t)(p - (uint8_t*)d_ws);

  bool basePath = false;
  int NB = 1;
  for (int nb = 16; nb >= 1; nb >>= 1) {
    if (fixed + 2 * S + (size_t)nb * CH32 <= ws_size) { basePath = true; NB = nb; break; }
  }
  if (!basePath) {
    for (int nb = 16; nb >= 1; nb >>= 1) {
      size_t need = fixed + S + (size_t)nb * (CH64 + CH32);
      if (need <= ws_size) { NB = nb; break; }
    }
  }

  // ---- common setup ----
  k_wprepC0<<<(64 * 288 + 255) / 256, 256, 0, stream>>>(w1, W1p);
  k_wprep64<<<(64 * 576 + 255) / 256, 256, 0, stream>>>(w2, W2p, 64);
  k_wprep64<<<(32 * 576 + 255) / 256, 256, 0, stream>>>(cw2, Wc2p, 32);
  k_bnfuse<<<1, 256, 0, stream>>>(g1, be1, m1, v1, b1, s1, t1, 64);
  k_bnfuse<<<1, 256, 0, stream>>>(g2, be2, m2, v2, b2, s2, t2, 64);
  k_bnfuse<<<1, 256, 0, stream>>>(cg1, cbe1, cm1, cv1, cb1, sc1, tc1, 64);
  k_bnfuse<<<1, 256, 0, stream>>>(cg2, cbe2, cm2, cv2, cb2, sc2, tc2, 32);
  k_windpart<<<512, 256, 0, stream>>>(env, wpart);
  k_windfin<<<16, 64, 0, stream>>>(wpart, windk, wke);
  k_copy<<<1024, 256, 0, stream>>>(fire0, evo);
  k_firemap<<<(16 * 66564 + 255) / 256, 256, 0, stream>>>(fire0, fmap, 16);

  if (basePath) {
    k_wprepC1env<<<(64 * 576 + 255) / 256, 256, 0, stream>>>(cw1, Wenv);
    k_wprepOh<<<(9 * 5 * 72 + 255) / 256, 256, 0, stream>>>(cw1, Woh);
    k_ident<<<1, 64, 0, stream>>>(idsc, idsh);

    f16* S1 = (f16*)(p);             // encoder tmp (padded); later base (unpadded)
    f16* S2 = (f16*)(p + S);         // envf (padded), encoder only
    f16* chunk = (f16*)(p + 2 * S);  // envin / h2 (NB imgs)
    f16* envin = chunk;
    f16* h2 = chunk;

    k_border<<<(16 * 1028 * 64 + 255) / 256, 256, 0, stream>>>(S1, 16, 64);
    k_border<<<(16 * 1028 * 64 + 255) / 256, 256, 0, stream>>>(S2, 16, 64);
    k_border<<<(NB * 1028 * 32 + 255) / 256, 256, 0, stream>>>(envin, NB, 32);

    const int gconv = NB * 64;
    for (int b0 = 0; b0 < 16; b0 += NB) {
      k_env2h<<<NB * 256, 256, 0, stream>>>(env + (size_t)b0 * 22 * HWSZ, envin, NB);
      k_convM4<32, 9, true, true><<<gconv, 256, 0, stream>>>(
          envin, W1p, s1, t1, S1 + (size_t)b0 * IMGP, NB);
      k_convM4<64, 18, true, true><<<gconv, 256, 0, stream>>>(
          S1 + (size_t)b0 * IMGP, W2p, s2, t2, S2 + (size_t)b0 * IMGP, NB);
      k_convM4<64, 18, false, false><<<gconv, 256, 0, stream>>>(
          S2 + (size_t)b0 * IMGP, Wenv, idsc, idsh, S1 + (size_t)b0 * IMGU, NB);
    }
    for (int t = 0; t < 5; ++t) {
      const float* fin = evo + (size_t)t * 1048576;
      float* fo = evo + (size_t)(t + 1) * 1048576;
      for (int b0 = 0; b0 < 16; b0 += NB) {
        k_convF<<<gconv, 256, 0, stream>>>(
            S1 + (size_t)b0 * IMGU, Wc2p, Woh, sc1, tc1, sc2, tc2,
            fmap + (size_t)b0 * 66564, h2, NB);
        k_step<<<NB * 256, 256, 0, stream>>>(
            h2, cw3, cb3, wke + (size_t)b0 * 9, fin + (size_t)b0 * HWSZ,
            fo + (size_t)b0 * HWSZ, (t == 4) ? out + (size_t)b0 * HWSZ : nullptr,
            fmap + (size_t)b0 * 66564);
      }
    }
  } else {
    // ---- fallback: exact r6/r12 pipeline ----
    k_wprepC1<<<(64 * 640 + 255) / 256, 256, 0, stream>>>(cw1, Wc1p);
    f16* envf = (f16*)p;
    f16* h1p = (f16*)(p + S);
    f16* chunk = (f16*)(p + S + (size_t)NB * CH64);
    f16* envin = chunk;
    f16* h2 = chunk;

    k_border<<<(16 * 1028 * 64 + 255) / 256, 256, 0, stream>>>(envf, 16, 64);
    k_border<<<(NB * 1028 * 64 + 255) / 256, 256, 0, stream>>>(h1p, NB, 64);
    k_border<<<(NB * 1028 * 32 + 255) / 256, 256, 0, stream>>>(envin, NB, 32);

    const int gconv = NB * 64;
    for (int b0 = 0; b0 < 16; b0 += NB) {
      k_env2h<<<NB * 256, 256, 0, stream>>>(env + (size_t)b0 * 22 * HWSZ, envin, NB);
      k_convM<32, 2, 9, false, true, false, true><<<gconv, 128, 0, stream>>>(
          envin, W1p, s1, t1, nullptr, h1p, NB);
      k_convM<64, 2, 18, false, true, false, true><<<gconv, 128, 0, stream>>>(
          h1p, W2p, s2, t2, nullptr, envf + (size_t)b0 * IMGP, NB);
    }
    for (int t = 0; t < 5; ++t) {
      const float* fin = evo + (size_t)t * 1048576;
      float* fo = evo + (size_t)(t + 1) * 1048576;
      for (int b0 = 0; b0 < 16; b0 += NB) {
        k_convM<64, 2, 20, true, true, false, true><<<gconv, 128, 0, stream>>>(
            envf + (size_t)b0 * IMGP, Wc1p, sc1, tc1, fmap + (size_t)b0 * 66564,
            h1p, NB);
        k_convM<64, 2, 18, false, false, true, true><<<gconv, 128, 0, stream>>>(
            h1p, Wc2p, sc2, tc2, nullptr, h2, NB);
        k_step<<<NB * 256, 256, 0, stream>>>(
            h2, cw3, cb3, wke + (size_t)b0 * 9, fin + (size_t)b0 * HWSZ,
            fo + (size_t)b0 * HWSZ, (t == 4) ? out + (size_t)b0 * HWSZ : nullptr,
            fmap + (size_t)b0 * 66564);
      }
    }
  }
}

// Round 16
// 851.143 us; speedup vs baseline: 2.0896x; 2.0896x over previous
//
#include <hip/hip_runtime.h>
#include <cstdint>
#include <cstddef>

// LearnableCA fire-spread, round 16: REVERT to the r14 optimum (859 us).
// r15's 4-wave convF spilled (VGPR 64, FETCH 768MB — same signature as r8);
// the 4-wave direction is conclusively dead. This is r14 verbatim:
// - algebraic cw1 split: one-time base conv + per-step in-register one-hot
// - k_convF: reg-staged h1 (T14 split), 6-slot ring, __syncthreads per phase
// - encoder convs: r6 schedule (8-slot ring, counted vmcnt, 2 waves/128T)

#define HWSZ 65536

typedef _Float16 f16;
typedef f16 f16x8 __attribute__((ext_vector_type(8)));
typedef f16 f16x4 __attribute__((ext_vector_type(4)));
typedef float f32x4 __attribute__((ext_vector_type(4)));

#define GLDS16(gp, lp)                                                        \
  __builtin_amdgcn_global_load_lds(                                           \
      (const __attribute__((address_space(1))) void*)(gp),                    \
      (__attribute__((address_space(3))) void*)(lp), 16, 0, 0)

// ---- conv1 weight prep: [64][22][3][3] -> [co][tap*32+ci], ci7 x64, pad->32 ----
__global__ void k_wprepC0(const float* __restrict__ src, f16* __restrict__ dst) {
  int i = blockIdx.x * 256 + threadIdx.x;
  if (i >= 64 * 288) return;
  int co = i / 288, k = i - co * 288;
  int tap = k >> 5, ci = k & 31;
  float v = 0.f;
  if (ci < 22) {
    v = src[(co * 22 + ci) * 9 + tap];
    if (ci == 7) v *= 64.f;
  }
  dst[i] = (f16)v;
}

// ---- fp16 weight prep: [co][ci 64][3][3] -> [co][tap*64+ci] ----
__global__ void k_wprep64(const float* __restrict__ src, f16* __restrict__ dst,
                          int COUT) {
  int i = blockIdx.x * 256 + threadIdx.x;
  if (i >= COUT * 576) return;
  int co = i / 576, k = i - co * 576;
  int tap = k >> 6, ci = k & 63;
  dst[i] = (f16)src[(co * 64 + ci) * 9 + tap];
}

// ---- cw1 env-part prep (stride-68 source): -> [co][tap*64+ci] ----
__global__ void k_wprepC1env(const float* __restrict__ src, f16* __restrict__ dst) {
  int i = blockIdx.x * 256 + threadIdx.x;
  if (i >= 64 * 576) return;
  int co = i / 576, k = i - co * 576;
  int tap = k >> 6, ci = k & 63;
  dst[i] = (f16)src[(co * 68 + ci) * 9 + tap];
}

// ---- cw1 one-hot table: [9][5][72] (tap, cls, co); cls=4 -> 0 ----
__global__ void k_wprepOh(const float* __restrict__ src, f16* __restrict__ dst) {
  int i = blockIdx.x * 256 + threadIdx.x;
  if (i >= 9 * 5 * 72) return;
  int tap = i / (5 * 72), r = i - tap * (5 * 72);
  int cls = r / 72, co = r - cls * 72;
  float v = 0.f;
  if (co < 64 && cls < 4) v = src[(co * 68 + 64 + cls) * 9 + tap];
  dst[i] = (f16)v;
}

// ---- cw1 full prep (fallback): 64 ci + one-hot block -> [co][640] ----
__global__ void k_wprepC1(const float* __restrict__ src, f16* __restrict__ dst) {
  int i = blockIdx.x * 256 + threadIdx.x;
  if (i >= 64 * 640) return;
  int co = i / 640, k = i - co * 640;
  float v;
  if (k < 576) {
    int tap = k >> 6, ci = k & 63;
    v = src[(co * 68 + ci) * 9 + tap];
  } else {
    int kl = k - 576;
    int oc = kl & 3, tp = kl >> 2;
    v = (tp < 9) ? src[(co * 68 + 64 + oc) * 9 + tp] : 0.f;
  }
  dst[i] = (f16)v;
}

// ---- fold BN + conv bias into per-channel scale/shift ----
__global__ void k_bnfuse(const float* __restrict__ g, const float* __restrict__ be,
                         const float* __restrict__ m, const float* __restrict__ v,
                         const float* __restrict__ bc, float* __restrict__ s,
                         float* __restrict__ t, int C) {
  int c = threadIdx.x;
  if (c < C) {
    float sc = g[c] * rsqrtf(v[c] + 1e-5f);
    s[c] = sc;
    t[c] = (bc[c] - m[c]) * sc + be[c];
  }
}

// ---- identity scale/shift for the base conv ----
__global__ void k_ident(float* __restrict__ s, float* __restrict__ t) {
  int c = threadIdx.x;
  if (c < 64) { s[c] = 1.f; t[c] = 0.f; }
}

// ---- wind reduction stage 1 ----
__global__ __launch_bounds__(256) void k_windpart(const float* __restrict__ env,
                                                  double* __restrict__ part) {
  int blk = blockIdx.x;
  int b = blk >> 5, j = blk & 31;
  const float4* a7 = (const float4*)(env + (((size_t)(b * 22 + 7)) << 16) + j * 2048);
  const float4* a8 = (const float4*)(env + (((size_t)(b * 22 + 8)) << 16) + j * 2048);
  int tid = threadIdx.x;
  double s7 = 0.0, s8 = 0.0;
  for (int i = tid; i < 512; i += 256) {
    float4 v = a7[i];
    s7 += (double)v.x + (double)v.y + (double)v.z + (double)v.w;
    float4 u = a8[i];
    s8 += (double)u.x + (double)u.y + (double)u.z + (double)u.w;
  }
  __shared__ double r7[256], r8[256];
  r7[tid] = s7; r8[tid] = s8;
  __syncthreads();
  for (int off = 128; off > 0; off >>= 1) {
    if (tid < off) { r7[tid] += r7[tid + off]; r8[tid] += r8[tid + off]; }
    __syncthreads();
  }
  if (tid == 0) {
    part[(b * 32 + j) * 2 + 0] = r7[0];
    part[(b * 32 + j) * 2 + 1] = r8[0];
  }
}

// ---- wind reduction stage 2 ----
__global__ void k_windfin(const double* __restrict__ part,
                          const float* __restrict__ wind_k, float* __restrict__ wke) {
  int b = blockIdx.x;
  if (threadIdx.x != 0) return;
  double s7 = 0.0, s8 = 0.0;
  for (int j = 0; j < 32; ++j) {
    s7 += part[(b * 32 + j) * 2 + 0];
    s8 += part[(b * 32 + j) * 2 + 1];
  }
  float wa = (float)(s7 * (1.0 / 65536.0));
  float wsp = (float)(s8 * (1.0 / 65536.0));
  float wsc = fminf(fmaxf(wsp * (1.f / 20.f), 0.f), 1.f);
  float wk[9];
#pragma unroll
  for (int tp = 0; tp < 9; ++tp) wk[tp] = 0.f;
  for (int d = 0; d < 8; ++d) {
    float diff = fabsf(wa - 45.f * (float)d);
    diff = fminf(diff, 360.f - diff);
    float dw = fmaxf(0.f, 1.f - diff * (1.f / 90.f));
    float eff = (dw > 0.1f && wsc > 0.1f) ? dw * wsc : 0.f;
    for (int tp = 0; tp < 9; ++tp) wk[tp] += eff * wind_k[d * 9 + tp];
  }
  for (int tp = 0; tp < 9; ++tp) wke[b * 9 + tp] = wk[tp];
}

__global__ void k_copy(const float* __restrict__ src, float* __restrict__ dst) {
  int i = blockIdx.x * 256 + threadIdx.x;
  ((float4*)dst)[i] = ((const float4*)src)[i];
}

// ---- zero the 1-px border of a padded NHWC buffer [n][258][258][C] ----
__global__ void k_border(f16* __restrict__ buf, int nimg, int C) {
  int i = blockIdx.x * 256 + threadIdx.x;
  int per = 1028 * C;
  if (i >= nimg * per) return;
  int img = i / per, r = i - img * per;
  int px = r / C, c = r - px * C;
  int h, w;
  if (px < 258) { h = 0; w = px; }
  else if (px < 516) { h = 257; w = px - 258; }
  else if (px < 772) { h = px - 515; w = 0; }
  else { h = px - 771; w = 257; }
  buf[((size_t)(img * 258 + h) * 258 + w) * C + c] = (f16)0.f;
}

// ---- env NCHW fp32 -> padded NHWC fp16 [258][258][32], ch7 * 1/64 ----
__global__ __launch_bounds__(256) void k_env2h(const float* __restrict__ env,
                                               f16* __restrict__ dst, int nimg) {
  int i = blockIdx.x * 256 + threadIdx.x;
  if (i >= (nimg << 16)) return;
  int b = i >> 16, hw = i & 65535;
  int h = hw >> 8, w = hw & 255;
  const float* sp = env + (((size_t)b * 22) << 16) + hw;
  f16 o[32];
#pragma unroll
  for (int c = 0; c < 22; ++c) {
    float v = sp[(size_t)c << 16];
    if (c == 7) v *= (1.f / 64.f);
    o[c] = (f16)v;
  }
#pragma unroll
  for (int c = 22; c < 32; ++c) o[c] = (f16)0.f;
  f16* dp = dst + ((size_t)(b * 258 + h + 1) * 258 + (w + 1)) * 32;
  *(f16x8*)(dp + 0) = *(f16x8*)&o[0];
  *(f16x8*)(dp + 8) = *(f16x8*)&o[8];
  *(f16x8*)(dp + 16) = *(f16x8*)&o[16];
  *(f16x8*)(dp + 24) = *(f16x8*)&o[24];
}

// ---- padded uint8 fire-class map: [b][258][258], border=4 ----
__global__ void k_firemap(const float* __restrict__ fire, unsigned char* __restrict__ map,
                          int nimg) {
  int i = blockIdx.x * 256 + threadIdx.x;
  if (i >= nimg * 66564) return;
  int b = i / 66564, r = i - b * 66564;
  int h = r / 258, w = r - h * 258;
  unsigned char v = 4;
  if (h >= 1 && h <= 256 && w >= 1 && w <= 256) {
    float f = fire[((size_t)b << 16) + ((h - 1) << 8) + (w - 1)];
    v = f < 0.25f ? 0 : (f < 0.75f ? 1 : 2);
  }
  map[i] = v;
}

// ---- MFMA conv (r6/r12 schedule): 8-slot ring, 32-row strips, 2 waves ----
template <int CIN, int NCS, int NS, bool ONEHOT, bool OUTPAD, bool PXSPLIT, bool RELU>
__global__ __launch_bounds__(128, 2) void k_convM(
    const f16* __restrict__ x, const f16* __restrict__ Wp,
    const float* __restrict__ scale, const float* __restrict__ shift,
    const unsigned char* __restrict__ fmap, f16* __restrict__ y, int NB) {
  constexpr int COUT = PXSPLIT ? NCS * 16 : NCS * 32;
  constexpr int KT = NS * 32;
  constexpr int CC = CIN / 8;
  constexpr int PERROW = 34 * CC;
  constexpr int ROWE = 34 * CIN;
  constexpr int PXW = PXSPLIT ? 1 : 2;
  constexpr int NH = CIN / 32;
  constexpr int VN0 = (CIN == 64) ? 6 : 4;
  constexpr int VN1 = (CIN == 64) ? 4 : 2;

  __shared__ __align__(16) f16 xs[8][ROWE];
  __shared__ float sst[2][COUT];

  int tid = threadIdx.x;
  int lane = tid & 63;
  int l15 = lane & 15;
  int g = (lane >> 4) & 3;
  int wco = tid >> 6;

  int d = blockIdx.x;
  int hsn = NB * 8;
  int ws = d / hsn;
  int t = d - ws * hsn;
  int b = t >> 3;
  int hs = t & 7;
  int w0 = ws * 32, h0 = hs * 32;

  int co_base = PXSPLIT ? 0 : wco * NCS * 16;
  int pxg = PXSPLIT ? wco * 16 : 0;

  f16x8 Af[NCS][NS];
  {
    const f16* wb = Wp + (size_t)(co_base + l15) * KT + g * 8;
#pragma unroll
    for (int cs = 0; cs < NCS; ++cs)
#pragma unroll
      for (int s = 0; s < NS; ++s)
        Af[cs][s] = *(const f16x8*)(wb + cs * 16 * KT + s * 32);
  }
  if (tid < COUT) {
    sst[0][tid] = scale[tid];
    sst[1][tid] = shift[tid];
  }

  auto stage_row = [&](int row) {
    int rs = row > 256 ? 256 : row;
    const f16* src = x + ((size_t)(b * 258 + rs + 1) * 258 + w0) * CIN;
    f16* dst = xs[(row + 1) & 7];
    for (int c = tid; c < PERROW; c += 128) {
      int px = c / CC, cc = c - px * CC;
      int sz = (CIN == 64) ? (px & 7) : ((px >> 1) & 3);
      GLDS16(src + px * CIN + ((cc ^ sz) << 3), dst + c * 8);
    }
  };

#define PHASE_SYNC()                                                      \
  do {                                                                    \
    if (wco == 0)                                                         \
      asm volatile("s_waitcnt vmcnt(%0)" ::"i"(VN0) : "memory");          \
    else                                                                  \
      asm volatile("s_waitcnt vmcnt(%0)" ::"i"(VN1) : "memory");          \
    __builtin_amdgcn_s_barrier();                                         \
    __builtin_amdgcn_sched_barrier(0);                                    \
  } while (0)

  stage_row(h0 - 1); stage_row(h0);
  stage_row(h0 + 1); stage_row(h0 + 2);
  stage_row(h0 + 3); stage_row(h0 + 4);
  PHASE_SYNC();

#pragma unroll 1
  for (int hp = h0; hp < h0 + 32; hp += 2) {
#pragma unroll
    for (int r2 = 0; r2 < 2; ++r2) {
      stage_row(hp + 5 + r2);
      int h = hp + r2;

      f32x4 acc[NCS][PXW];
#pragma unroll
      for (int cs = 0; cs < NCS; ++cs)
#pragma unroll
        for (int p = 0; p < PXW; ++p) acc[cs][p] = (f32x4){0.f, 0.f, 0.f, 0.f};

      int ia[PXW], ib[PXW], ic[PXW];
      if (ONEHOT) {
        int ta = 2 * g, tb = ta + 1;
        int dya = ta / 3, dxa = ta - 3 * dya;
        int dyb = tb / 3, dxb = tb - 3 * dyb;
#pragma unroll
        for (int pxb = 0; pxb < PXW; ++pxb) {
          int pxa = pxg + pxb * 16 + l15;
          ia[pxb] = fmap[(size_t)(b * 258 + h + dya) * 258 + w0 + pxa + dxa];
          ib[pxb] = fmap[(size_t)(b * 258 + h + dyb) * 258 + w0 + pxa + dxb];
          ic[pxb] = fmap[(size_t)(b * 258 + h + 2) * 258 + w0 + pxa + 2];
        }
      }

      const f16* sp0 = xs[h & 7];
      const f16* sp1 = xs[(h + 1) & 7];
      const f16* sp2 = xs[(h + 2) & 7];
#pragma unroll
      for (int tap = 0; tap < 9; ++tap) {
        const int dy = tap / 3, dx = tap - 3 * (tap / 3);
        const f16* sp = (dy == 0) ? sp0 : ((dy == 1) ? sp1 : sp2);
#pragma unroll
        for (int pxb = 0; pxb < PXW; ++pxb) {
          int pxd = pxg + pxb * 16 + l15 + dx;
          int sz = (CIN == 64) ? (pxd & 7) : ((pxd >> 1) & 3);
#pragma unroll
          for (int half = 0; half < NH; ++half) {
            f16x8 bb = *(const f16x8*)(sp + pxd * CIN + (((g + 4 * half) ^ sz) << 3));
#pragma unroll
            for (int cs = 0; cs < NCS; ++cs)
              acc[cs][pxb] = __builtin_amdgcn_mfma_f32_16x16x32_f16(
                  Af[cs][tap * NH + half], bb, acc[cs][pxb], 0, 0, 0);
          }
        }
      }
      if (ONEHOT) {
#pragma unroll
        for (int pxb = 0; pxb < PXW; ++pxb) {
          f16x8 b18, b19;
#pragma unroll
          for (int j = 0; j < 4; ++j) {
            b18[j] = (f16)((ia[pxb] == j) ? 1.f : 0.f);
            b18[j + 4] = (f16)((ib[pxb] == j) ? 1.f : 0.f);
            b19[j] = (f16)((g == 0 && ic[pxb] == j) ? 1.f : 0.f);
            b19[j + 4] = (f16)0.f;
          }
#pragma unroll
          for (int cs = 0; cs < NCS; ++cs) {
            acc[cs][pxb] = __builtin_amdgcn_mfma_f32_16x16x32_f16(
                Af[cs][NS - 2], b18, acc[cs][pxb], 0, 0, 0);
            acc[cs][pxb] = __builtin_amdgcn_mfma_f32_16x16x32_f16(
                Af[cs][NS - 1], b19, acc[cs][pxb], 0, 0, 0);
          }
        }
      }
#pragma unroll
      for (int cs = 0; cs < NCS; ++cs) {
        int cb = co_base + cs * 16 + 4 * g;
        f32x4 sv = *(const f32x4*)&sst[0][cb];
        f32x4 tv = *(const f32x4*)&sst[1][cb];
#pragma unroll
        for (int pxb = 0; pxb < PXW; ++pxb) {
          int px = pxg + pxb * 16 + l15;
          f16x4 o;
#pragma unroll
          for (int r = 0; r < 4; ++r) {
            float v = acc[cs][pxb][r] * sv[r] + tv[r];
            o[r] = (f16)(RELU ? fmaxf(v, 0.f) : v);
          }
          size_t oi =
              OUTPAD ? ((size_t)(b * 258 + h + 1) * 258 + (w0 + px + 1)) * 64 + cb
                     : ((size_t)(b * 256 + h) * 256 + (w0 + px)) * COUT + cb;
          *(f16x4*)&y[oi] = o;
        }
      }
    }
    PHASE_SYNC();
  }
#undef PHASE_SYNC
}

// ---- fused step conv: h1 staged in-kernel from base+onehot, then 3x3 -> h2 ----
// base: [NB][256][256][64] unpadded fp16 (pre-BN env part of cw1).
// Per wave: 16 couts (co_base = wco*16), 32 px (2 groups of 16). 6-slot ring.
__global__ __launch_bounds__(128, 2) void k_convF(
    const f16* __restrict__ base, const f16* __restrict__ Wp,
    const f16* __restrict__ Woh,
    const float* __restrict__ s1v, const float* __restrict__ t1v,
    const float* __restrict__ s2v, const float* __restrict__ t2v,
    const unsigned char* __restrict__ fmap, f16* __restrict__ y, int NB) {
  constexpr int NS = 18, KT = NS * 32;
  __shared__ __align__(16) f16 xs[6][34 * 64];   // 26.1 KB h1 ring
  __shared__ f16 tbl[9 * 5 * 72];                // one-hot table
  __shared__ float sA[2][64];                    // h1 BN scale/shift
  __shared__ float sB[2][32];                    // h2 BN scale/shift

  int tid = threadIdx.x;
  int lane = tid & 63;
  int l15 = lane & 15;
  int g = (lane >> 4) & 3;
  int wco = tid >> 6;

  int d = blockIdx.x;
  int hsn = NB * 8;
  int ws = d / hsn;
  int t = d - ws * hsn;
  int b = t >> 3;
  int hs = t & 7;
  int w0 = ws * 32, h0 = hs * 32;
  int co_base = wco * 16;

  f16x8 Af[NS];
  {
    const f16* wb = Wp + (size_t)(co_base + l15) * KT + g * 8;
#pragma unroll
    for (int s = 0; s < NS; ++s) Af[s] = *(const f16x8*)(wb + s * 32);
  }
  for (int i = tid; i < 9 * 5 * 72; i += 128) tbl[i] = Woh[i];
  if (tid < 64) sA[0][tid] = s1v[tid];
  else sA[1][tid - 64] = t1v[tid - 64];
  if (tid < 32) sB[0][tid] = s2v[tid];
  else if (tid < 64) sB[1][tid - 32] = t2v[tid - 32];
  __syncthreads();

  const unsigned char* fmb = fmap + (size_t)b * 66564;

  // full (non-overlapped) staging of rows rbase, rbase+1
  auto stage_pair = [&](int rbase) {
    for (int c = tid; c < 544; c += 128) {
      int r2 = c >= 272 ? 1 : 0;
      int cc = c - r2 * 272;
      int px = cc >> 3, q = cc & 7;
      int row = rbase + r2;
      int col = w0 - 1 + px;
      f16* dst = &xs[(row + 1) % 6][px * 64 + ((q ^ (px & 7)) << 3)];
      if ((unsigned)row < 256u && (unsigned)col < 256u) {
        f16x8 a = *(const f16x8*)&base[(((size_t)(b * 256 + row)) * 256 + col) * 64 + q * 8];
        int cls[9];
#pragma unroll
        for (int tap = 0; tap < 9; ++tap)
          cls[tap] = fmb[(size_t)(row + tap / 3) * 258 + col + tap % 3];
#pragma unroll
        for (int tap = 0; tap < 9; ++tap)
          a = a + *(const f16x8*)&tbl[(tap * 5 + cls[tap]) * 72 + q * 8];
        f16x8 o;
#pragma unroll
        for (int j = 0; j < 8; ++j) {
          float v = (float)a[j] * sA[0][q * 8 + j] + sA[1][q * 8 + j];
          o[j] = (f16)fmaxf(v, 0.f);
        }
        *(f16x8*)dst = o;
      } else {
        f16x8 z = {};
        *(f16x8*)dst = z;
      }
    }
  };

  stage_pair(h0 - 1);
  stage_pair(h0 + 1);
  __syncthreads();

#pragma unroll 1
  for (int hp = h0; hp < h0 + 32; hp += 2) {
    // ---- issue stage loads for rows hp+3, hp+4 (main: 4 chunks, same px) ----
    int c0 = 4 * tid;
    int rM2 = c0 >= 272 ? 1 : 0;
    int ccM = c0 - rM2 * 272;
    int pxM = ccM >> 3, qM = ccM & 7;  // qM in {0,4}
    int rowM = hp + 3 + rM2;
    int colM = w0 - 1 + pxM;
    bool okM = ((unsigned)rowM < 256u) && ((unsigned)colM < 256u);
    f16x8 sm0 = {}, sm1 = {}, sm2 = {}, sm3 = {};
    if (okM) {
      const f16* bp = &base[(((size_t)(b * 256 + rowM)) * 256 + colM) * 64 + qM * 8];
      sm0 = *(const f16x8*)(bp + 0);
      sm1 = *(const f16x8*)(bp + 8);
      sm2 = *(const f16x8*)(bp + 16);
      sm3 = *(const f16x8*)(bp + 24);
    }
    int px4 = 0, q4 = 0, col4 = 0;
    bool ok4 = false;
    f16x8 se = {};
    if (tid < 32) {
      int cc4 = 240 + tid;  // chunk 512+tid -> row1, cc = 240..271
      px4 = cc4 >> 3; q4 = cc4 & 7;
      col4 = w0 - 1 + px4;
      ok4 = ((unsigned)(hp + 4) < 256u) && ((unsigned)col4 < 256u);
      if (ok4)
        se = *(const f16x8*)&base[(((size_t)(b * 256 + hp + 4)) * 256 + col4) * 64 + q4 * 8];
    }
    __builtin_amdgcn_sched_barrier(0);

    // ---- MFMA rows hp, hp+1 + h2 epilogue ----
#pragma unroll
    for (int rr = 0; rr < 2; ++rr) {
      int h = hp + rr;
      f32x4 acc[2];
      acc[0] = (f32x4){0.f, 0.f, 0.f, 0.f};
      acc[1] = (f32x4){0.f, 0.f, 0.f, 0.f};
      const f16* sp0 = xs[h % 6];
      const f16* sp1 = xs[(h + 1) % 6];
      const f16* sp2 = xs[(h + 2) % 6];
#pragma unroll
      for (int tap = 0; tap < 9; ++tap) {
        const int dy = tap / 3, dx = tap - 3 * (tap / 3);
        const f16* sp = (dy == 0) ? sp0 : ((dy == 1) ? sp1 : sp2);
#pragma unroll
        for (int pxb = 0; pxb < 2; ++pxb) {
          int pxd = pxb * 16 + l15 + dx;
          int sz = pxd & 7;
#pragma unroll
          for (int half = 0; half < 2; ++half) {
            f16x8 bb = *(const f16x8*)(sp + pxd * 64 + (((g + 4 * half) ^ sz) << 3));
            acc[pxb] = __builtin_amdgcn_mfma_f32_16x16x32_f16(
                Af[tap * 2 + half], bb, acc[pxb], 0, 0, 0);
          }
        }
      }
      int cb = co_base + 4 * g;
      f32x4 sv = *(const f32x4*)&sB[0][cb];
      f32x4 tv = *(const f32x4*)&sB[1][cb];
#pragma unroll
      for (int pxb = 0; pxb < 2; ++pxb) {
        int px = pxb * 16 + l15;
        f16x4 o;
#pragma unroll
        for (int r = 0; r < 4; ++r)
          o[r] = (f16)fmaxf(acc[pxb][r] * sv[r] + tv[r], 0.f);
        *(f16x4*)&y[((size_t)(b * 256 + h) * 256 + (w0 + px)) * 32 + cb] = o;
      }
    }
    __builtin_amdgcn_sched_barrier(0);

    // ---- transform + ds_write staged rows ----
    {
      f16* dstM = &xs[(rowM + 1) % 6][pxM * 64];
      if (okM) {
        int cls[9];
#pragma unroll
        for (int tap = 0; tap < 9; ++tap)
          cls[tap] = fmb[(size_t)(rowM + tap / 3) * 258 + colM + tap % 3];
#define XFORM(SRC, QOFF)                                                      \
  {                                                                           \
    int q_ = qM + QOFF;                                                       \
    f16x8 a_ = SRC;                                                           \
    _Pragma("unroll") for (int tap = 0; tap < 9; ++tap)                       \
        a_ = a_ + *(const f16x8*)&tbl[(tap * 5 + cls[tap]) * 72 + q_ * 8];    \
    f16x8 o_;                                                                 \
    _Pragma("unroll") for (int j = 0; j < 8; ++j) {                           \
      float v_ = (float)a_[j] * sA[0][q_ * 8 + j] + sA[1][q_ * 8 + j];        \
      o_[j] = (f16)fmaxf(v_, 0.f);                                           \
    }                                                                         \
    *(f16x8*)(dstM + ((q_ ^ (pxM & 7)) << 3)) = o_;                           \
  }
        XFORM(sm0, 0)
        XFORM(sm1, 1)
        XFORM(sm2, 2)
        XFORM(sm3, 3)
#undef XFORM
      } else {
        f16x8 z = {};
        *(f16x8*)(dstM + (((qM + 0) ^ (pxM & 7)) << 3)) = z;
        *(f16x8*)(dstM + (((qM + 1) ^ (pxM & 7)) << 3)) = z;
        *(f16x8*)(dstM + (((qM + 2) ^ (pxM & 7)) << 3)) = z;
        *(f16x8*)(dstM + (((qM + 3) ^ (pxM & 7)) << 3)) = z;
      }
      if (tid < 32) {
        f16* dst4 = &xs[(hp + 5) % 6][px4 * 64 + ((q4 ^ (px4 & 7)) << 3)];
        if (ok4) {
          int cls[9];
#pragma unroll
          for (int tap = 0; tap < 9; ++tap)
            cls[tap] = fmb[(size_t)(hp + 4 + tap / 3) * 258 + col4 + tap % 3];
          f16x8 a_ = se;
#pragma unroll
          for (int tap = 0; tap < 9; ++tap)
            a_ = a_ + *(const f16x8*)&tbl[(tap * 5 + cls[tap]) * 72 + q4 * 8];
          f16x8 o_;
#pragma unroll
          for (int j = 0; j < 8; ++j) {
            float v_ = (float)a_[j] * sA[0][q4 * 8 + j] + sA[1][q4 * 8 + j];
            o_[j] = (f16)fmaxf(v_, 0.f);
          }
          *(f16x8*)dst4 = o_;
        } else {
          f16x8 z = {};
          *(f16x8*)dst4 = z;
        }
      }
    }
    __syncthreads();
  }
}

// ---- fused 1x1 conv (32->4) + softmax + wind conv + fire update + next map ----
__global__ __launch_bounds__(256) void k_step(
    const f16* __restrict__ h2, const float* __restrict__ cw3,
    const float* __restrict__ cb3, const float* __restrict__ wke,
    const float* __restrict__ fin, float* __restrict__ fout,
    float* __restrict__ fout2, unsigned char* __restrict__ mapout) {
  __shared__ float wl[4][32];
  __shared__ float bl[4];
  __shared__ float wk[9];
  int tid = threadIdx.x;
  if (tid < 128) wl[tid >> 5][tid & 31] = cw3[tid];
  if (tid < 4) bl[tid] = cb3[tid];
  int bx = blockIdx.x;
  int b = bx >> 8, h = bx & 255;
  if (tid < 9) wk[tid] = wke[b * 9 + tid];
  __syncthreads();
  int w = tid;
  const f16x8* hp8 = (const f16x8*)(h2 + ((size_t)(b * 256 + h) * 256 + w) * 32);
  float l0 = bl[0], l1 = bl[1], l2 = bl[2], l3 = bl[3];
#pragma unroll
  for (int q = 0; q < 4; ++q) {
    f16x8 v8 = hp8[q];
#pragma unroll
    for (int j = 0; j < 8; ++j) {
      float v = (float)v8[j];
      int c = q * 8 + j;
      l0 += v * wl[0][c];
      l1 += v * wl[1][c];
      l2 += v * wl[2][c];
      l3 += v * wl[3][c];
    }
  }
  float mx = fmaxf(fmaxf(l0, l1), fmaxf(l2, l3));
  float e0 = expf(l0 - mx), e1 = expf(l1 - mx), e2 = expf(l2 - mx), e3 = expf(l3 - mx);
  float inv = 1.f / (e0 + e1 + e2 + e3);
  float p1 = e1 * inv, p2 = e2 * inv;
  const float* fp = fin + ((size_t)b << 16);
  float wacc = 0.f;
#pragma unroll
  for (int tap = 0; tap < 9; ++tap) {
    int dy = tap / 3 - 1, dx = tap % 3 - 1;
    int hh = h + dy, ww2 = w + dx;
    float f = ((unsigned)hh < 256u && (unsigned)ww2 < 256u) ? fp[(hh << 8) + ww2] : 0.f;
    wacc += wk[tap] * f;
  }
  float boost = 0.3f / (1.f + expf(-wacc));
  float fcur = fp[(h << 8) + w];
  float target = 0.5f * p1 + 0.5f * boost + p2;
  float fn = 0.7f * fcur + 0.3f * target;
  fn = fminf(fmaxf(fn, 0.f), 1.f);
  size_t o = ((size_t)b << 16) + (h << 8) + w;
  fout[o] = fn;
  if (fout2) fout2[o] = fn;
  mapout[(size_t)(b * 258 + h + 1) * 258 + (w + 1)] =
      fn < 0.25f ? (unsigned char)0 : (fn < 0.75f ? (unsigned char)1 : (unsigned char)2);
}

extern "C" void kernel_launch(void* const* d_in, const int* in_sizes, int n_in,
                              void* d_out, int out_size, void* d_ws, size_t ws_size,
                              hipStream_t stream) {
  const float* env = (const float*)d_in[0];
  const float* fire0 = (const float*)d_in[1];
  const float* w1 = (const float*)d_in[2];
  const float* b1 = (const float*)d_in[3];
  const float* g1 = (const float*)d_in[4];
  const float* be1 = (const float*)d_in[5];
  const float* m1 = (const float*)d_in[6];
  const float* v1 = (const float*)d_in[7];
  const float* w2 = (const float*)d_in[8];
  const float* b2 = (const float*)d_in[9];
  const float* g2 = (const float*)d_in[10];
  const float* be2 = (const float*)d_in[11];
  const float* m2 = (const float*)d_in[12];
  const float* v2 = (const float*)d_in[13];
  const float* cw1 = (const float*)d_in[14];
  const float* cb1 = (const float*)d_in[15];
  const float* cg1 = (const float*)d_in[16];
  const float* cbe1 = (const float*)d_in[17];
  const float* cm1 = (const float*)d_in[18];
  const float* cv1 = (const float*)d_in[19];
  const float* cw2 = (const float*)d_in[20];
  const float* cb2 = (const float*)d_in[21];
  const float* cg2 = (const float*)d_in[22];
  const float* cbe2 = (const float*)d_in[23];
  const float* cm2 = (const float*)d_in[24];
  const float* cv2 = (const float*)d_in[25];
  const float* cw3 = (const float*)d_in[26];
  const float* cb3 = (const float*)d_in[27];
  const float* windk = (const float*)d_in[28];
  // d_in[29] = num_steps (fixed 5)

  float* out = (float*)d_out;
  float* evo = out + 1048576;

  // ---- fixed small region ----
  uint8_t* p = (uint8_t*)d_ws;
  f16* W1p = (f16*)p;           p += 64 * 288 * 2;
  f16* W2p = (f16*)p;           p += 64 * 576 * 2;
  f16* Wc1p = (f16*)p;          p += 64 * 640 * 2;
  f16* Wenv = (f16*)p;          p += 64 * 576 * 2;
  f16* Woh = (f16*)p;           p += 9 * 5 * 72 * 2;
  f16* Wc2p = (f16*)p;          p += 32 * 576 * 2;
  float* s1 = (float*)p;        p += 64 * 4;
  float* t1 = (float*)p;        p += 64 * 4;
  float* s2 = (float*)p;        p += 64 * 4;
  float* t2 = (float*)p;        p += 64 * 4;
  float* sc1 = (float*)p;       p += 64 * 4;
  float* tc1 = (float*)p;       p += 64 * 4;
  float* sc2 = (float*)p;       p += 64 * 4;
  float* tc2 = (float*)p;       p += 64 * 4;
  float* idsc = (float*)p;      p += 64 * 4;
  float* idsh = (float*)p;      p += 64 * 4;
  float* wke = (float*)p;       p += 1024;
  double* wpart = (double*)p;   p += 16 * 32 * 2 * 8;
  unsigned char* fmap = p;      p += 16 * 66564 + 1024;

  const size_t IMGP = (size_t)258 * 258 * 64;
  const size_t IMGP32 = (size_t)258 * 258 * 32;
  const size_t IMGU = (size_t)65536 * 64;
  const size_t S = 16 * IMGP * 2;
  const size_t CH64 = IMGP * 2;
  const size_t CH32 = IMGP32 * 2;
  size_t fixed = (size_t)(p - (uint8_t*)d_ws);

  bool basePath = false;
  int NB = 1;
  for (int nb = 16; nb >= 1; nb >>= 1) {
    if (fixed + 2 * S + (size_t)nb * CH32 <= ws_size) { basePath = true; NB = nb; break; }
  }
  if (!basePath) {
    for (int nb = 16; nb >= 1; nb >>= 1) {
      size_t need = fixed + S + (size_t)nb * (CH64 + CH32);
      if (need <= ws_size) { NB = nb; break; }
    }
  }

  // ---- common setup ----
  k_wprepC0<<<(64 * 288 + 255) / 256, 256, 0, stream>>>(w1, W1p);
  k_wprep64<<<(64 * 576 + 255) / 256, 256, 0, stream>>>(w2, W2p, 64);
  k_wprep64<<<(32 * 576 + 255) / 256, 256, 0, stream>>>(cw2, Wc2p, 32);
  k_bnfuse<<<1, 256, 0, stream>>>(g1, be1, m1, v1, b1, s1, t1, 64);
  k_bnfuse<<<1, 256, 0, stream>>>(g2, be2, m2, v2, b2, s2, t2, 64);
  k_bnfuse<<<1, 256, 0, stream>>>(cg1, cbe1, cm1, cv1, cb1, sc1, tc1, 64);
  k_bnfuse<<<1, 256, 0, stream>>>(cg2, cbe2, cm2, cv2, cb2, sc2, tc2, 32);
  k_windpart<<<512, 256, 0, stream>>>(env, wpart);
  k_windfin<<<16, 64, 0, stream>>>(wpart, windk, wke);
  k_copy<<<1024, 256, 0, stream>>>(fire0, evo);
  k_firemap<<<(16 * 66564 + 255) / 256, 256, 0, stream>>>(fire0, fmap, 16);

  if (basePath) {
    k_wprepC1env<<<(64 * 576 + 255) / 256, 256, 0, stream>>>(cw1, Wenv);
    k_wprepOh<<<(9 * 5 * 72 + 255) / 256, 256, 0, stream>>>(cw1, Woh);
    k_ident<<<1, 64, 0, stream>>>(idsc, idsh);

    f16* S1 = (f16*)(p);             // encoder tmp (padded); later base (unpadded)
    f16* S2 = (f16*)(p + S);         // envf (padded), encoder only
    f16* chunk = (f16*)(p + 2 * S);  // envin / h2 (NB imgs)
    f16* envin = chunk;
    f16* h2 = chunk;

    k_border<<<(16 * 1028 * 64 + 255) / 256, 256, 0, stream>>>(S1, 16, 64);
    k_border<<<(16 * 1028 * 64 + 255) / 256, 256, 0, stream>>>(S2, 16, 64);
    k_border<<<(NB * 1028 * 32 + 255) / 256, 256, 0, stream>>>(envin, NB, 32);

    const int gconv = NB * 64;
    for (int b0 = 0; b0 < 16; b0 += NB) {
      k_env2h<<<NB * 256, 256, 0, stream>>>(env + (size_t)b0 * 22 * HWSZ, envin, NB);
      k_convM<32, 2, 9, false, true, false, true><<<gconv, 128, 0, stream>>>(
          envin, W1p, s1, t1, nullptr, S1 + (size_t)b0 * IMGP, NB);
      k_convM<64, 2, 18, false, true, false, true><<<gconv, 128, 0, stream>>>(
          S1 + (size_t)b0 * IMGP, W2p, s2, t2, nullptr, S2 + (size_t)b0 * IMGP, NB);
      k_convM<64, 2, 18, false, false, false, false><<<gconv, 128, 0, stream>>>(
          S2 + (size_t)b0 * IMGP, Wenv, idsc, idsh, nullptr,
          S1 + (size_t)b0 * IMGU, NB);
    }
    for (int t = 0; t < 5; ++t) {
      const float* fin = evo + (size_t)t * 1048576;
      float* fo = evo + (size_t)(t + 1) * 1048576;
      for (int b0 = 0; b0 < 16; b0 += NB) {
        k_convF<<<gconv, 128, 0, stream>>>(
            S1 + (size_t)b0 * IMGU, Wc2p, Woh, sc1, tc1, sc2, tc2,
            fmap + (size_t)b0 * 66564, h2, NB);
        k_step<<<NB * 256, 256, 0, stream>>>(
            h2, cw3, cb3, wke + (size_t)b0 * 9, fin + (size_t)b0 * HWSZ,
            fo + (size_t)b0 * HWSZ, (t == 4) ? out + (size_t)b0 * HWSZ : nullptr,
            fmap + (size_t)b0 * 66564);
      }
    }
  } else {
    // ---- fallback: exact r6/r12 pipeline ----
    k_wprepC1<<<(64 * 640 + 255) / 256, 256, 0, stream>>>(cw1, Wc1p);
    f16* envf = (f16*)p;
    f16* h1p = (f16*)(p + S);
    f16* chunk = (f16*)(p + S + (size_t)NB * CH64);
    f16* envin = chunk;
    f16* h2 = chunk;

    k_border<<<(16 * 1028 * 64 + 255) / 256, 256, 0, stream>>>(envf, 16, 64);
    k_border<<<(NB * 1028 * 64 + 255) / 256, 256, 0, stream>>>(h1p, NB, 64);
    k_border<<<(NB * 1028 * 32 + 255) / 256, 256, 0, stream>>>(envin, NB, 32);

    const int gconv = NB * 64;
    for (int b0 = 0; b0 < 16; b0 += NB) {
      k_env2h<<<NB * 256, 256, 0, stream>>>(env + (size_t)b0 * 22 * HWSZ, envin, NB);
      k_convM<32, 2, 9, false, true, false, true><<<gconv, 128, 0, stream>>>(
          envin, W1p, s1, t1, nullptr, h1p, NB);
      k_convM<64, 2, 18, false, true, false, true><<<gconv, 128, 0, stream>>>(
          h1p, W2p, s2, t2, nullptr, envf + (size_t)b0 * IMGP, NB);
    }
    for (int t = 0; t < 5; ++t) {
      const float* fin = evo + (size_t)t * 1048576;
      float* fo = evo + (size_t)(t + 1) * 1048576;
      for (int b0 = 0; b0 < 16; b0 += NB) {
        k_convM<64, 2, 20, true, true, false, true><<<gconv, 128, 0, stream>>>(
            envf + (size_t)b0 * IMGP, Wc1p, sc1, tc1, fmap + (size_t)b0 * 66564,
            h1p, NB);
        k_convM<64, 2, 18, false, false, true, true><<<gconv, 128, 0, stream>>>(
            h1p, Wc2p, sc2, tc2, nullptr, h2, NB);
        k_step<<<NB * 256, 256, 0, stream>>>(
            h2, cw3, cb3, wke + (size_t)b0 * 9, fin + (size_t)b0 * HWSZ,
            fo + (size_t)b0 * HWSZ, (t == 4) ? out + (size_t)b0 * HWSZ : nullptr,
            fmap + (size_t)b0 * 66564);
      }
    }
  }
}